// Round 1
// baseline (756.024 us; speedup 1.0000x reference)
//
#include <hip/hip_runtime.h>

// GraphConvolution on MI355X (gfx950) — full-integer i8 pipeline.
//
// Algebra: Xq/act_delta = m in [0,15] (i8), Wq/wgt_delta in [-7,7] (i8),
// Sq/sup_delta = m2 in [0,15] (i8). Both matmuls are exact in i32. Only the
// adj->i8 quantization (scale 127) introduces error (~1 bf16-ULP of output).
//
// Round-4 restructure (this round):
//   - adjq fused into GEMM1's dispatch as blockIdx.z==1 blocks: adjq is pure
//     BW and independent of GEMM1 (compute-bound) -> time = max, not sum.
//   - combine fused into GEMM2 epilogue via threadfence+ticket (last-arriving
//     split-K block sums its register acc with partner's i32 partial and
//     writes f32 out). Removes a dispatch + 32 MB of re-read; tail overlaps.
//   - wstats+xquant fused (independent) -> one dispatch.
//   - T2 LDS swizzle: chunk' = (chunk + (row>>1)) & 3 within each 64B LDS row,
//     applied by pre-swizzling the GLOBAL source of global_load_lds (dest must
//     stay linear, rule #21). Read uses the same bijection. Fixes the ~4-way
//     ds_read_b128 bank-group aliasing; may be drain-hidden in this 2-phase
//     structure (regime gate) — carried as a free rider.
// Dispatches: memset, pre(wstats|xquant), wquant, gemm1|adjq, gemm2(+combine).
//
// Grid keeps x = m-strip so linear_id % 8 == m%8: all n/z blocks sharing an
// adj strip land on the same XCD/L2 (round-2 fix: 848 MB -> ~0.13 GB fetch).

#define AS_G __attribute__((address_space(1)))
#define AS_L __attribute__((address_space(3)))

typedef int i32x4 __attribute__((ext_vector_type(4)));
typedef char c8 __attribute__((ext_vector_type(8)));
typedef char c16 __attribute__((ext_vector_type(16)));

static __device__ __forceinline__ void gload_lds16(const char* g, char* l) {
  __builtin_amdgcn_global_load_lds((const AS_G unsigned int*)g,
                                   (AS_L unsigned int*)l, 16, 0, 0);
}

// ---- fused: wstats (blocks 0..255, f64 atomics) + xquant (blocks 256..) ----
__global__ void pre_kernel(const float* __restrict__ w, double* __restrict__ stats,
                           const float* __restrict__ x, char* __restrict__ xq,
                           const float* __restrict__ alpha_p, int wn, int xn) {
  if (blockIdx.x < 256) {
    double s = 0.0, ss = 0.0;
    for (int i = (blockIdx.x * 256 + threadIdx.x) * 4; i < wn; i += 256 * 256 * 4) {
      float4 v = *(const float4*)&w[i];
      s += (double)v.x + (double)v.y + (double)v.z + (double)v.w;
      ss += (double)v.x * v.x + (double)v.y * v.y + (double)v.z * v.z + (double)v.w * v.w;
    }
#pragma unroll
    for (int off = 32; off > 0; off >>= 1) {
      s  += __shfl_down(s, off);
      ss += __shfl_down(ss, off);
    }
    if ((threadIdx.x & 63) == 0) {
      atomicAdd(&stats[0], s);
      atomicAdd(&stats[1], ss);
    }
  } else {
    int i = ((blockIdx.x - 256) * 256 + threadIdx.x) * 8;
    if (i >= xn) return;
    const float alpha = *alpha_p;
    float4 v0 = *(const float4*)&x[i];
    float4 v1 = *(const float4*)&x[i + 4];
    c8 o;
    o[0] = (char)(int)rintf(fminf(v0.x / alpha, 1.f) * 15.f);
    o[1] = (char)(int)rintf(fminf(v0.y / alpha, 1.f) * 15.f);
    o[2] = (char)(int)rintf(fminf(v0.z / alpha, 1.f) * 15.f);
    o[3] = (char)(int)rintf(fminf(v0.w / alpha, 1.f) * 15.f);
    o[4] = (char)(int)rintf(fminf(v1.x / alpha, 1.f) * 15.f);
    o[5] = (char)(int)rintf(fminf(v1.y / alpha, 1.f) * 15.f);
    o[6] = (char)(int)rintf(fminf(v1.z / alpha, 1.f) * 15.f);
    o[7] = (char)(int)rintf(fminf(v1.w / alpha, 1.f) * 15.f);
    *(c8*)&xq[i] = o;
  }
}

// ------------- weight quant -> i8 levels, transposed (OUTF x INF) -------------
__global__ void wquant_kernel(const float* __restrict__ w, char* __restrict__ wt,
                              const double* __restrict__ stats,
                              const float* __restrict__ alpha_p) {
  int idx = blockIdx.x * 256 + threadIdx.x;
  const double cnt = 1048576.0;
  const double mean = stats[0] / cnt;
  const double var = (stats[1] - stats[0] * mean) / (cnt - 1.0);  // ddof=1
  const float meanf = (float)mean;
  const float stdf = (float)sqrt(var);
  const float alpha = *alpha_p;
  const int n = idx >> 10;          // out-feature
  const int k = idx & 1023;         // in-feature
  float wn = (w[(size_t)k * 1024 + n] - meanf) / stdf;
  float wc = fminf(fmaxf(wn / alpha, -1.f), 1.f);
  wt[idx] = (char)(int)copysignf(rintf(fabsf(wc) * 7.f), wc);  // -7..7
}

// ---------------- i8 GEMM body: C[M,N] = A[M,LDK] * B[N,LDK]^T (i32 acc) -----
// RELUQ: epilogue scale*relu*quant -> i8, store transposed Ct[N][M].
// else : split-K x2: write raw i32 partial, last-arriving z combines with
//        partner's partial (threadfence+ticket) and writes f32 out.
// AF32 : A is f32, quantized in-kernel via VALU+ds_write (ws-too-small path).
// T2 swizzle: LDS(row, cs) holds Global(row, (cs - (row>>1))&3); reads fetch
// Global chunk c at LDS chunk (c + (row>>1))&3. Bijective per row; octets of
// the ds_read_b128 hit 8 distinct bank-groups (conflict-free read pattern).
template <bool RELUQ, bool AF32>
static __device__ __forceinline__ void gemm_body(
    const void* __restrict__ Av, const char* __restrict__ B, void* __restrict__ Cv,
    float* __restrict__ outp, int* __restrict__ tickets,
    const int M, const int N, const int LDK, const int Kspan, const int zidx,
    const float* s0p, const float* s1p, const float* s2p) {
  __shared__ __align__(16) char As[128 * 64];
  __shared__ __align__(16) char Bs[128 * 64];
  __shared__ int s_old;

  const int tid = threadIdx.x;
  const int lane = tid & 63;
  const int wv = tid >> 6;
  const int wm = wv >> 1, wn = wv & 1;
  const int m0 = blockIdx.x * 128, n0 = blockIdx.y * 128;  // x=m: XCD shares adj strip
  const int kz = zidx * Kspan;

  const int srow = tid >> 2;  // 16B-granule staging; source chunk pre-swizzled
  const int scol = (((tid & 3) + 4 - ((tid >> 3) & 3)) & 3) * 16;
  const int frow = tid >> 1;  // AF32 staging: 32 floats/thread
  const int ft = (tid & 1) * 2;        // global 16B-chunk base for AF32
  const int fsh = (tid >> 2) & 3;      // (frow>>1)&3 swizzle shift

  i32x4 acc[4][4];
#pragma unroll
  for (int i = 0; i < 4; ++i)
#pragma unroll
    for (int j = 0; j < 4; ++j) acc[i][j] = (i32x4){0, 0, 0, 0};

  const int lrow = lane & 15;
  const int q16 = (((lane >> 4) + (lrow >> 1)) & 3) * 16;  // swizzled read chunk

  for (int kt = kz; kt < kz + Kspan; kt += 64) {
    __syncthreads();
    if (AF32) {
      const float* Af = (const float*)Av;
      const float* src = Af + (size_t)(m0 + frow) * LDK + kt + (tid & 1) * 32;
      c16 p0, p1;
#pragma unroll
      for (int j = 0; j < 4; ++j) {
        float4 v = *(const float4*)(src + 4 * j);
        p0[4 * j + 0] = (char)(int)rintf(v.x * 127.f);
        p0[4 * j + 1] = (char)(int)rintf(v.y * 127.f);
        p0[4 * j + 2] = (char)(int)rintf(v.z * 127.f);
        p0[4 * j + 3] = (char)(int)rintf(v.w * 127.f);
      }
#pragma unroll
      for (int j = 0; j < 4; ++j) {
        float4 v = *(const float4*)(src + 16 + 4 * j);
        p1[4 * j + 0] = (char)(int)rintf(v.x * 127.f);
        p1[4 * j + 1] = (char)(int)rintf(v.y * 127.f);
        p1[4 * j + 2] = (char)(int)rintf(v.z * 127.f);
        p1[4 * j + 3] = (char)(int)rintf(v.w * 127.f);
      }
      *(c16*)&As[frow * 64 + (((ft + 0) + fsh) & 3) * 16] = p0;
      *(c16*)&As[frow * 64 + (((ft + 1) + fsh) & 3) * 16] = p1;
    } else {
      const char* Ab = (const char*)Av;
      gload_lds16(Ab + (size_t)(m0 + srow) * LDK + kt + scol, &As[wv * 1024]);
      gload_lds16(Ab + (size_t)(m0 + 64 + srow) * LDK + kt + scol, &As[4096 + wv * 1024]);
    }
    gload_lds16(B + (size_t)(n0 + srow) * LDK + kt + scol, &Bs[wv * 1024]);
    gload_lds16(B + (size_t)(n0 + 64 + srow) * LDK + kt + scol, &Bs[4096 + wv * 1024]);
    __syncthreads();

    i32x4 af[4], bfr[4];
#pragma unroll
    for (int mi = 0; mi < 4; ++mi)
      af[mi] = *(const i32x4*)&As[(wm * 64 + mi * 16 + lrow) * 64 + q16];
#pragma unroll
    for (int ni = 0; ni < 4; ++ni)
      bfr[ni] = *(const i32x4*)&Bs[(wn * 64 + ni * 16 + lrow) * 64 + q16];
#pragma unroll
    for (int mi = 0; mi < 4; ++mi)
#pragma unroll
      for (int ni = 0; ni < 4; ++ni)
        acc[mi][ni] =
            __builtin_amdgcn_mfma_i32_16x16x64_i8(af[mi], bfr[ni], acc[mi][ni], 0, 0, 0);
  }

  // C/D layout: col(n) = lane&15, row(m) = (lane>>4)*4 + reg  (dtype-indep, m121-128)
  const int qr = (lane >> 4) * 4;
  if (RELUQ) {
    const float d_act = *s0p / 15.f;   // act_alpha / (2^4-1)
    const float d_wgt = *s1p / 7.f;    // wgt_alpha / (2^3-1)
    const float a2 = *s2p;
    char* Ct = (char*)Cv;  // N x M i8
#pragma unroll
    for (int mi = 0; mi < 4; ++mi) {
      const int mb = m0 + wm * 64 + mi * 16 + qr;
#pragma unroll
      for (int ni = 0; ni < 4; ++ni) {
        const int n = n0 + wn * 64 + ni * 16 + lrow;
        char4 pk;
#pragma unroll
        for (int r = 0; r < 4; ++r) {
          float s = (float)acc[mi][ni][r] * d_act * d_wgt;  // exact int * deltas
          s = fmaxf(s, 0.f);                                // relu
          float xc = fminf(s / a2, 1.f);                    // act_quant (no low clamp)
          ((char*)&pk)[r] = (char)(int)rintf(xc * 15.f);    // m2 in 0..15
        }
        *(char4*)&Ct[(size_t)n * M + mb] = pk;
      }
    }
  } else {
    // write own i32 partial
    int* P = (int*)Cv + (size_t)zidx * M * N;
#pragma unroll
    for (int mi = 0; mi < 4; ++mi) {
      const int mb = m0 + wm * 64 + mi * 16 + qr;
#pragma unroll
      for (int ni = 0; ni < 4; ++ni) {
        const int n = n0 + wn * 64 + ni * 16 + lrow;
#pragma unroll
        for (int r = 0; r < 4; ++r)
          P[(size_t)(mb + r) * N + n] = acc[mi][ni][r];
      }
    }
    // release partial, take ticket; last-arriving z combines (G12/G16 pattern:
    // device-scope fence makes stores LLC-visible across XCDs before the
    // device-scope atomic; winner fences again (acquire) before reading).
    __threadfence();
    __syncthreads();
    if (tid == 0) s_old = atomicAdd(&tickets[blockIdx.y * gridDim.x + blockIdx.x], 1);
    __syncthreads();
    if (s_old == 0) return;  // block-uniform: partner combines
    __threadfence();
    const int* Pp = (const int*)Cv + (size_t)(1 - zidx) * M * N;
    const float sc = (*s2p) * (1.f / 15.f) * (1.f / 127.f);
#pragma unroll
    for (int mi = 0; mi < 4; ++mi) {
      const int mb = m0 + wm * 64 + mi * 16 + qr;
#pragma unroll
      for (int ni = 0; ni < 4; ++ni) {
        const int n = n0 + wn * 64 + ni * 16 + lrow;
#pragma unroll
        for (int r = 0; r < 4; ++r)
          outp[(size_t)(mb + r) * N + n] =
              (float)(acc[mi][ni][r] + Pp[(size_t)(mb + r) * N + n]) * sc;
      }
    }
  }
}

template <bool RELUQ, bool AF32>
__global__ __launch_bounds__(256, 4) void gemm_i8_kernel(
    const void* __restrict__ Av, const char* __restrict__ B, void* __restrict__ Cv,
    float* __restrict__ outp, int* __restrict__ tickets,
    const int M, const int N, const int LDK, const int Kspan,
    const float* __restrict__ s0p, const float* __restrict__ s1p,
    const float* __restrict__ s2p) {
  gemm_body<RELUQ, AF32>(Av, B, Cv, outp, tickets, M, N, LDK, Kspan, blockIdx.z,
                         s0p, s1p, s2p);
}

// ---- fused GEMM1 (z=0, compute-bound) + adj f32->i8 quant (z=1, BW-bound) ----
__global__ __launch_bounds__(256, 4) void gemm1_adjq_kernel(
    const void* __restrict__ Av, const char* __restrict__ B, void* __restrict__ Cv,
    const float* __restrict__ s0p, const float* __restrict__ s1p,
    const float* __restrict__ s2p,
    const float* __restrict__ adj, char* __restrict__ adjq, long long an) {
  if (blockIdx.z == 1) {
    const long long bid = (long long)blockIdx.y * gridDim.x + blockIdx.x;  // 0..511
    for (long long i = (bid * 256 + threadIdx.x) * 16; i < an;
         i += (long long)512 * 256 * 16) {
      c16 r;
#pragma unroll
      for (int j = 0; j < 4; ++j) {
        float4 v = *(const float4*)&adj[i + 4 * j];
        r[4 * j + 0] = (char)(int)rintf(v.x * 127.f);
        r[4 * j + 1] = (char)(int)rintf(v.y * 127.f);
        r[4 * j + 2] = (char)(int)rintf(v.z * 127.f);
        r[4 * j + 3] = (char)(int)rintf(v.w * 127.f);
      }
      *(c16*)&adjq[i] = r;
    }
    return;
  }
  gemm_body<true, false>(Av, B, Cv, nullptr, nullptr, 8192, 1024, 1024, 1024, 0,
                         s0p, s1p, s2p);
}

extern "C" void kernel_launch(void* const* d_in, const int* in_sizes, int n_in,
                              void* d_out, int out_size, void* d_ws, size_t ws_size,
                              hipStream_t stream) {
  const float* input  = (const float*)d_in[0];   // 8192 x 1024
  const float* adj    = (const float*)d_in[1];   // 8192 x 8192
  // d_in[2] adj_scaling_factor = 2.0: pow2, cancels exactly in f32
  const float* weight = (const float*)d_in[3];   // 1024 x 1024
  const float* wgt_alpha  = (const float*)d_in[4];
  const float* act_alpha  = (const float*)d_in[5];
  const float* act_alpha2 = (const float*)d_in[6];
  float* out = (float*)d_out;                    // 8192 x 1024 f32

  constexpr int NN = 8192, INF = 1024, OUTF = 1024;
  constexpr size_t MB = 1024 * 1024;
  constexpr size_t HDR = 64 * 1024;

  char* ws = (char*)d_ws;
  double* stats = (double*)ws;                   // 16 B
  int* tickets = (int*)(ws + 4096);              // 512 x 4 B split-K tickets
  char* WtI  = ws + HDR;                         // OUTF x INF   (1 MB)
  char* XqI  = ws + HDR + 1 * MB;                // NN x INF     (8 MB)
  char* StI  = ws + HDR + 9 * MB;                // OUTF x NN    (8 MB)
  int*  Pbuf = (int*)(ws + HDR + 17 * MB);       // 2 x NN x OUTF i32 (64 MB)
  char* AdjQ = ws + HDR + 81 * MB;               // NN x NN      (64 MB)
  const size_t need = HDR + 145 * MB;

  hipMemsetAsync(ws, 0, 8192, stream);           // stats + tickets

  pre_kernel<<<256 + (NN * INF / 8) / 256, 256, 0, stream>>>(
      weight, stats, input, XqI, act_alpha, INF * OUTF, NN * INF);
  wquant_kernel<<<(INF * OUTF) / 256, 256, 0, stream>>>(weight, WtI, stats, wgt_alpha);

  if (ws_size >= need) {
    // GEMM1: Xq[8192x1024] @ Wt[1024x1024]^T -> Sq^T i8 [1024 x 8192], with
    // adjq (256 MB read / 64 MB write) riding the same dispatch on z=1.
    gemm1_adjq_kernel<<<dim3(NN / 128, OUTF / 128, 2), 256, 0, stream>>>(
        XqI, WtI, StI, act_alpha, wgt_alpha, act_alpha2, adj, AdjQ, (long long)NN * NN);
    // GEMM2: AdjQ[8192x8192] @ St[1024x8192]^T, split-K x2, fused combine.
    gemm_i8_kernel<false, false><<<dim3(NN / 128, OUTF / 128, 2), 256, 0, stream>>>(
        AdjQ, StI, Pbuf, out, tickets, NN, OUTF, NN, NN / 2,
        nullptr, nullptr, act_alpha2);
  } else {
    gemm_i8_kernel<true, false><<<dim3(NN / 128, OUTF / 128, 1), 256, 0, stream>>>(
        XqI, WtI, StI, nullptr, nullptr, NN, OUTF, INF, INF,
        act_alpha, wgt_alpha, act_alpha2);
    gemm_i8_kernel<false, true><<<dim3(NN / 128, OUTF / 128, 2), 256, 0, stream>>>(
        adj, StI, Pbuf, out, tickets, NN, OUTF, NN, NN / 2,
        nullptr, nullptr, act_alpha2);
  }
}

// Round 2
// 552.039 us; speedup vs baseline: 1.3695x; 1.3695x over previous
//
#include <hip/hip_runtime.h>

// GraphConvolution on MI355X (gfx950) — full-integer i8 pipeline.
//
// Algebra: Xq/act_delta = m in [0,15] (i8), Wq/wgt_delta in [-7,7] (i8),
// Sq/sup_delta = m2 in [0,15] (i8). Both matmuls are exact in i32. Only the
// adj->i8 quantization (scale 127) introduces error (~1 bf16-ULP of output).
//
// Round-5 (this round):
//   - REVERTED round-4 fence-combine: __threadfence() at device scope lowers
//     to L2 writeback/invalidate on gfx950 (per-XCD L2 non-coherence) -> 2048
//     whole-L2 flushes destroyed co-resident blocks' working sets; GEMM2 went
//     165 -> 335 us with everything idle (MfmaUtil 8%, HBM 7%). Lesson: no
//     agent-scope fences inside hot kernels on this chip.
//   - Split-K reduction now via f32 atomicAdd straight into out (pre-zeroed):
//     atomics are device-scope coherent WITHOUT L2 flush. i32 partials < 2^24
//     so (float)acc is exact; f32 add is commutative -> deterministic. Kills
//     the combine dispatch + 128 MB partial traffic + 64 MB workspace.
//   - T3-min 2-phase: double-buffered LDS, next-tile global_load_lds issued
//     BEFORE current tile's ds_read+MFMA, ONE barrier per K-step (barrier's
//     implicit vmcnt(0)/lgkmcnt(0) provides all ordering). Stage latency now
//     hides under compute.
//   - Kept: pre(wstats|xquant) fusion, gemm1|adjq z-fusion, T2 LDS swizzle
//     (bank conflicts measured 0; prereq for a future 8-phase port).
// Dispatches: memset(stats), memset(out), pre, wquant, gemm1|adjq, gemm2.
//
// Grid keeps x = m-strip so linear_id % 8 == m%8: all n/z blocks sharing an
// adj strip land on the same XCD/L2 (round-2 fix: 848 MB -> ~0.13 GB fetch).

#define AS_G __attribute__((address_space(1)))
#define AS_L __attribute__((address_space(3)))

typedef int i32x4 __attribute__((ext_vector_type(4)));
typedef char c8 __attribute__((ext_vector_type(8)));
typedef char c16 __attribute__((ext_vector_type(16)));

static __device__ __forceinline__ void gload_lds16(const char* g, char* l) {
  __builtin_amdgcn_global_load_lds((const AS_G unsigned int*)g,
                                   (AS_L unsigned int*)l, 16, 0, 0);
}

// ---- fused: wstats (blocks 0..255, f64 atomics) + xquant (blocks 256..) ----
__global__ void pre_kernel(const float* __restrict__ w, double* __restrict__ stats,
                           const float* __restrict__ x, char* __restrict__ xq,
                           const float* __restrict__ alpha_p, int wn, int xn) {
  if (blockIdx.x < 256) {
    double s = 0.0, ss = 0.0;
    for (int i = (blockIdx.x * 256 + threadIdx.x) * 4; i < wn; i += 256 * 256 * 4) {
      float4 v = *(const float4*)&w[i];
      s += (double)v.x + (double)v.y + (double)v.z + (double)v.w;
      ss += (double)v.x * v.x + (double)v.y * v.y + (double)v.z * v.z + (double)v.w * v.w;
    }
#pragma unroll
    for (int off = 32; off > 0; off >>= 1) {
      s  += __shfl_down(s, off);
      ss += __shfl_down(ss, off);
    }
    if ((threadIdx.x & 63) == 0) {
      atomicAdd(&stats[0], s);
      atomicAdd(&stats[1], ss);
    }
  } else {
    int i = ((blockIdx.x - 256) * 256 + threadIdx.x) * 8;
    if (i >= xn) return;
    const float alpha = *alpha_p;
    float4 v0 = *(const float4*)&x[i];
    float4 v1 = *(const float4*)&x[i + 4];
    c8 o;
    o[0] = (char)(int)rintf(fminf(v0.x / alpha, 1.f) * 15.f);
    o[1] = (char)(int)rintf(fminf(v0.y / alpha, 1.f) * 15.f);
    o[2] = (char)(int)rintf(fminf(v0.z / alpha, 1.f) * 15.f);
    o[3] = (char)(int)rintf(fminf(v0.w / alpha, 1.f) * 15.f);
    o[4] = (char)(int)rintf(fminf(v1.x / alpha, 1.f) * 15.f);
    o[5] = (char)(int)rintf(fminf(v1.y / alpha, 1.f) * 15.f);
    o[6] = (char)(int)rintf(fminf(v1.z / alpha, 1.f) * 15.f);
    o[7] = (char)(int)rintf(fminf(v1.w / alpha, 1.f) * 15.f);
    *(c8*)&xq[i] = o;
  }
}

// ------------- weight quant -> i8 levels, transposed (OUTF x INF) -------------
__global__ void wquant_kernel(const float* __restrict__ w, char* __restrict__ wt,
                              const double* __restrict__ stats,
                              const float* __restrict__ alpha_p) {
  int idx = blockIdx.x * 256 + threadIdx.x;
  const double cnt = 1048576.0;
  const double mean = stats[0] / cnt;
  const double var = (stats[1] - stats[0] * mean) / (cnt - 1.0);  // ddof=1
  const float meanf = (float)mean;
  const float stdf = (float)sqrt(var);
  const float alpha = *alpha_p;
  const int n = idx >> 10;          // out-feature
  const int k = idx & 1023;         // in-feature
  float wn = (w[(size_t)k * 1024 + n] - meanf) / stdf;
  float wc = fminf(fmaxf(wn / alpha, -1.f), 1.f);
  wt[idx] = (char)(int)copysignf(rintf(fabsf(wc) * 7.f), wc);  // -7..7
}

// ---------------- i8 GEMM body: C[M,N] = A[M,LDK] * B[N,LDK]^T (i32 acc) -----
// RELUQ: epilogue scale*relu*quant -> i8, store transposed Ct[N][M].
// else : split-K: epilogue atomicAdd((float)acc * sc) into pre-zeroed f32 out.
//        Exact: |acc| < 2^24; f32 add commutative -> deterministic.
// AF32 : A is f32, quantized in-kernel via VALU+ds_write (ws-too-small path).
// T2 swizzle: LDS(row, c) holds Global(row, (c - (row>>1))&3); reads fetch
// Global chunk g at LDS chunk (g + (row>>1))&3. Conflict-free ds_read_b128.
// 2-phase: dbuf LDS; next-tile stage issued before current compute; one
// barrier per K-step (its implicit vmcnt(0)+lgkmcnt(0) orders everything).
template <bool RELUQ, bool AF32>
static __device__ __forceinline__ void gemm_body(
    const void* __restrict__ Av, const char* __restrict__ B, void* __restrict__ Cv,
    float* __restrict__ outp,
    const int M, const int N, const int LDK, const int Kspan, const int zidx,
    const float* s0p, const float* s1p, const float* s2p) {
  __shared__ __align__(16) char As[2][128 * 64];
  __shared__ __align__(16) char Bs[2][128 * 64];

  const int tid = threadIdx.x;
  const int lane = tid & 63;
  const int wv = tid >> 6;
  const int wm = wv >> 1, wn = wv & 1;
  const int m0 = blockIdx.x * 128, n0 = blockIdx.y * 128;  // x=m: XCD shares adj strip
  const int kz = zidx * Kspan;

  const int srow = tid >> 2;  // 16B-granule staging; source chunk pre-swizzled
  const int scol = (((tid & 3) + 4 - ((tid >> 3) & 3)) & 3) * 16;
  const int frow = tid >> 1;  // AF32 staging: 32 floats/thread
  const int ft = (tid & 1) * 2;        // global 16B-chunk base for AF32
  const int fsh = (tid >> 2) & 3;      // (frow>>1)&3 swizzle shift

  i32x4 acc[4][4];
#pragma unroll
  for (int i = 0; i < 4; ++i)
#pragma unroll
    for (int j = 0; j < 4; ++j) acc[i][j] = (i32x4){0, 0, 0, 0};

  const int lrow = lane & 15;
  const int q16 = (((lane >> 4) + (lrow >> 1)) & 3) * 16;  // swizzled read chunk

  auto stage = [&](int b, int kt) {
    if (AF32) {
      const float* Af = (const float*)Av;
      const float* src = Af + (size_t)(m0 + frow) * LDK + kt + (tid & 1) * 32;
      c16 p0, p1;
#pragma unroll
      for (int j = 0; j < 4; ++j) {
        float4 v = *(const float4*)(src + 4 * j);
        p0[4 * j + 0] = (char)(int)rintf(v.x * 127.f);
        p0[4 * j + 1] = (char)(int)rintf(v.y * 127.f);
        p0[4 * j + 2] = (char)(int)rintf(v.z * 127.f);
        p0[4 * j + 3] = (char)(int)rintf(v.w * 127.f);
      }
#pragma unroll
      for (int j = 0; j < 4; ++j) {
        float4 v = *(const float4*)(src + 16 + 4 * j);
        p1[4 * j + 0] = (char)(int)rintf(v.x * 127.f);
        p1[4 * j + 1] = (char)(int)rintf(v.y * 127.f);
        p1[4 * j + 2] = (char)(int)rintf(v.z * 127.f);
        p1[4 * j + 3] = (char)(int)rintf(v.w * 127.f);
      }
      *(c16*)&As[b][frow * 64 + (((ft + 0) + fsh) & 3) * 16] = p0;
      *(c16*)&As[b][frow * 64 + (((ft + 1) + fsh) & 3) * 16] = p1;
    } else {
      const char* Ab = (const char*)Av;
      gload_lds16(Ab + (size_t)(m0 + srow) * LDK + kt + scol, &As[b][wv * 1024]);
      gload_lds16(Ab + (size_t)(m0 + 64 + srow) * LDK + kt + scol,
                  &As[b][4096 + wv * 1024]);
    }
    gload_lds16(B + (size_t)(n0 + srow) * LDK + kt + scol, &Bs[b][wv * 1024]);
    gload_lds16(B + (size_t)(n0 + 64 + srow) * LDK + kt + scol,
                &Bs[b][4096 + wv * 1024]);
  };

  const int nt = Kspan / 64;
  stage(0, kz);
  __syncthreads();  // implicit vmcnt(0): buf0 ready

  for (int t = 0; t < nt; ++t) {
    const int cur = t & 1;
    if (t + 1 < nt) stage(cur ^ 1, kz + (t + 1) * 64);  // in flight during compute

    i32x4 af[4], bfr[4];
#pragma unroll
    for (int mi = 0; mi < 4; ++mi)
      af[mi] = *(const i32x4*)&As[cur][(wm * 64 + mi * 16 + lrow) * 64 + q16];
#pragma unroll
    for (int ni = 0; ni < 4; ++ni)
      bfr[ni] = *(const i32x4*)&Bs[cur][(wn * 64 + ni * 16 + lrow) * 64 + q16];
#pragma unroll
    for (int mi = 0; mi < 4; ++mi)
#pragma unroll
      for (int ni = 0; ni < 4; ++ni)
        acc[mi][ni] =
            __builtin_amdgcn_mfma_i32_16x16x64_i8(af[mi], bfr[ni], acc[mi][ni], 0, 0, 0);

    __syncthreads();  // drains next-tile stage (vmcnt) + this tile's reads (lgkm)
  }

  // C/D layout: col(n) = lane&15, row(m) = (lane>>4)*4 + reg  (dtype-indep, m121-128)
  const int qr = (lane >> 4) * 4;
  if (RELUQ) {
    const float d_act = *s0p / 15.f;   // act_alpha / (2^4-1)
    const float d_wgt = *s1p / 7.f;    // wgt_alpha / (2^3-1)
    const float a2 = *s2p;
    char* Ct = (char*)Cv;  // N x M i8
#pragma unroll
    for (int mi = 0; mi < 4; ++mi) {
      const int mb = m0 + wm * 64 + mi * 16 + qr;
#pragma unroll
      for (int ni = 0; ni < 4; ++ni) {
        const int n = n0 + wn * 64 + ni * 16 + lrow;
        char4 pk;
#pragma unroll
        for (int r = 0; r < 4; ++r) {
          float s = (float)acc[mi][ni][r] * d_act * d_wgt;  // exact int * deltas
          s = fmaxf(s, 0.f);                                // relu
          float xc = fminf(s / a2, 1.f);                    // act_quant (no low clamp)
          ((char*)&pk)[r] = (char)(int)rintf(xc * 15.f);    // m2 in 0..15
        }
        *(char4*)&Ct[(size_t)n * M + mb] = pk;
      }
    }
  } else {
    // split-K reduce: atomic f32 accumulate into pre-zeroed out. No fences.
    const float sc = (*s2p) * (1.f / 15.f) * (1.f / 127.f);
#pragma unroll
    for (int mi = 0; mi < 4; ++mi) {
      const int mb = m0 + wm * 64 + mi * 16 + qr;
#pragma unroll
      for (int ni = 0; ni < 4; ++ni) {
        const int n = n0 + wn * 64 + ni * 16 + lrow;
#pragma unroll
        for (int r = 0; r < 4; ++r)
          atomicAdd(&outp[(size_t)(mb + r) * N + n], (float)acc[mi][ni][r] * sc);
      }
    }
  }
}

template <bool RELUQ, bool AF32>
__global__ __launch_bounds__(256, 4) void gemm_i8_kernel(
    const void* __restrict__ Av, const char* __restrict__ B, void* __restrict__ Cv,
    float* __restrict__ outp,
    const int M, const int N, const int LDK, const int Kspan,
    const float* __restrict__ s0p, const float* __restrict__ s1p,
    const float* __restrict__ s2p) {
  gemm_body<RELUQ, AF32>(Av, B, Cv, outp, M, N, LDK, Kspan, blockIdx.z,
                         s0p, s1p, s2p);
}

// ---- fused GEMM1 (z=0, compute-bound) + adj f32->i8 quant (z=1, BW-bound) ----
__global__ __launch_bounds__(256, 4) void gemm1_adjq_kernel(
    const void* __restrict__ Av, const char* __restrict__ B, void* __restrict__ Cv,
    const float* __restrict__ s0p, const float* __restrict__ s1p,
    const float* __restrict__ s2p,
    const float* __restrict__ adj, char* __restrict__ adjq, long long an) {
  if (blockIdx.z == 1) {
    const long long bid = (long long)blockIdx.y * gridDim.x + blockIdx.x;  // 0..511
    for (long long i = (bid * 256 + threadIdx.x) * 16; i < an;
         i += (long long)512 * 256 * 16) {
      c16 r;
#pragma unroll
      for (int j = 0; j < 4; ++j) {
        float4 v = *(const float4*)&adj[i + 4 * j];
        r[4 * j + 0] = (char)(int)rintf(v.x * 127.f);
        r[4 * j + 1] = (char)(int)rintf(v.y * 127.f);
        r[4 * j + 2] = (char)(int)rintf(v.z * 127.f);
        r[4 * j + 3] = (char)(int)rintf(v.w * 127.f);
      }
      *(c16*)&adjq[i] = r;
    }
    return;
  }
  gemm_body<true, false>(Av, B, Cv, nullptr, 8192, 1024, 1024, 1024, 0,
                         s0p, s1p, s2p);
}

extern "C" void kernel_launch(void* const* d_in, const int* in_sizes, int n_in,
                              void* d_out, int out_size, void* d_ws, size_t ws_size,
                              hipStream_t stream) {
  const float* input  = (const float*)d_in[0];   // 8192 x 1024
  const float* adj    = (const float*)d_in[1];   // 8192 x 8192
  // d_in[2] adj_scaling_factor = 2.0: pow2, cancels exactly in f32
  const float* weight = (const float*)d_in[3];   // 1024 x 1024
  const float* wgt_alpha  = (const float*)d_in[4];
  const float* act_alpha  = (const float*)d_in[5];
  const float* act_alpha2 = (const float*)d_in[6];
  float* out = (float*)d_out;                    // 8192 x 1024 f32

  constexpr int NN = 8192, INF = 1024, OUTF = 1024;
  constexpr size_t MB = 1024 * 1024;
  constexpr size_t HDR = 64 * 1024;

  char* ws = (char*)d_ws;
  double* stats = (double*)ws;                   // 16 B
  char* WtI  = ws + HDR;                         // OUTF x INF   (1 MB)
  char* XqI  = ws + HDR + 1 * MB;                // NN x INF     (8 MB)
  char* StI  = ws + HDR + 9 * MB;                // OUTF x NN    (8 MB)
  char* AdjQ = ws + HDR + 17 * MB;               // NN x NN      (64 MB)
  const size_t need = HDR + 81 * MB;

  hipMemsetAsync(stats, 0, 256, stream);
  hipMemsetAsync(out, 0, (size_t)NN * OUTF * sizeof(float), stream);  // atomic dst

  pre_kernel<<<256 + (NN * INF / 8) / 256, 256, 0, stream>>>(
      weight, stats, input, XqI, act_alpha, INF * OUTF, NN * INF);
  wquant_kernel<<<(INF * OUTF) / 256, 256, 0, stream>>>(weight, WtI, stats, wgt_alpha);

  if (ws_size >= need) {
    // GEMM1: Xq[8192x1024] @ Wt[1024x1024]^T -> Sq^T i8 [1024 x 8192], with
    // adjq (256 MB read / 64 MB write) riding the same dispatch on z=1.
    gemm1_adjq_kernel<<<dim3(NN / 128, OUTF / 128, 2), 256, 0, stream>>>(
        XqI, WtI, StI, act_alpha, wgt_alpha, act_alpha2, adj, AdjQ, (long long)NN * NN);
    // GEMM2: AdjQ[8192x8192] @ St[1024x8192]^T, split-K x2, atomic f32 reduce.
    gemm_i8_kernel<false, false><<<dim3(NN / 128, OUTF / 128, 2), 256, 0, stream>>>(
        AdjQ, StI, nullptr, out, NN, OUTF, NN, NN / 2, nullptr, nullptr, act_alpha2);
  } else {
    gemm_i8_kernel<true, false><<<dim3(NN / 128, OUTF / 128, 1), 256, 0, stream>>>(
        XqI, WtI, StI, nullptr, NN, OUTF, INF, INF,
        act_alpha, wgt_alpha, act_alpha2);
    gemm_i8_kernel<false, true><<<dim3(NN / 128, OUTF / 128, 2), 256, 0, stream>>>(
        adj, StI, nullptr, out, NN, OUTF, NN, NN / 2, nullptr, nullptr, act_alpha2);
  }
}